// Round 1
// 573.242 us; speedup vs baseline: 1.0651x; 1.0651x over previous
//
#include <hip/hip_runtime.h>

// ---------------------------------------------------------------------------
// MoE FFN: SEQ=8192, IN_DIM=1024, HID=2048, 8 experts, topk=2, gelu(tanh) gate
// R4: gemm1 rewritten to the 8-phase 256-row schedule (T3+T4 counted vmcnt,
// T5 setprio, T2 XOR swizzle kept). 8 waves, BM=256, 128 U-cols + 128 G-cols
// per block, BK=64, 128KB dbuf LDS, vmcnt(2) only at phases 4/8 (one
// half-tile in flight across each wait). gemm2/casts/route/combine unchanged.
// ---------------------------------------------------------------------------

#define SEQ 8192
#define IN_DIM 1024
#define HID 2048
#define NEXP 8
#define TOPK 2
#define NSLOT (SEQ * TOPK)

#define BM 128
#define BK 64
#define MAX_TILES 136
#define BM1 256
#define MAX_T1 72

typedef unsigned short ushort_t;
typedef __bf16 bf16x8 __attribute__((ext_vector_type(8)));
typedef float f32x4 __attribute__((ext_vector_type(4)));

__device__ __forceinline__ ushort_t f2bf(float f) {
    union { float f; unsigned u; } v;
    v.f = f;
    unsigned r = v.u + 0x7FFFu + ((v.u >> 16) & 1u);
    return (ushort_t)(r >> 16);
}

__device__ __forceinline__ float gelu_tanh(float x) {
    float u = 0.7978845608028654f * x * (1.0f + 0.044715f * x * x);
    return x / (1.0f + __expf(-2.0f * u));
}

__device__ __forceinline__ void async16(const void* g, void* l) {
    __builtin_amdgcn_global_load_lds(
        (const __attribute__((address_space(1))) unsigned int*)g,
        (__attribute__((address_space(3))) unsigned int*)l, 16, 0, 0);
}

// pipeline barriers for gemm2 (unchanged 2-phase loop)
__device__ __forceinline__ void wait8_barrier() {
    asm volatile("s_waitcnt vmcnt(8)\ns_barrier" ::: "memory");
}
__device__ __forceinline__ void wait0_barrier() {
    asm volatile("s_waitcnt vmcnt(0)\ns_barrier" ::: "memory");
}
__device__ __forceinline__ void lds_barrier() {
    asm volatile("s_waitcnt lgkmcnt(0)\ns_barrier" ::: "memory");
}

// ---------------------------------------------------------------------------
__global__ void cast_bf16_kernel(const float* __restrict__ in,
                                 ushort_t* __restrict__ out, int n) {
    int i = (blockIdx.x * blockDim.x + threadIdx.x) * 4;
    if (i >= n) return;
    float4 v = *(const float4*)(in + i);
    union { ushort_t u[4]; uint2 v; } o;
    o.u[0] = f2bf(v.x); o.u[1] = f2bf(v.y);
    o.u[2] = f2bf(v.z); o.u[3] = f2bf(v.w);
    *(uint2*)(out + i) = o.v;
}

// down_proj [8][2048][1024] fp32 -> [8][1024][2048] bf16
__global__ void transpose_cast_kernel(const float* __restrict__ in,
                                      ushort_t* __restrict__ out) {
    __shared__ float tile[32][33];
    int e = blockIdx.z;
    int d0 = blockIdx.x * 32, h0 = blockIdx.y * 32;
    int tx = threadIdx.x & 31, ty = threadIdx.x >> 5;
    const float* src = in + (size_t)e * HID * IN_DIM;
    for (int j = 0; j < 32; j += 8)
        tile[ty + j][tx] = src[(size_t)(h0 + ty + j) * IN_DIM + d0 + tx];
    __syncthreads();
    ushort_t* dst = out + (size_t)e * IN_DIM * HID;
    for (int j = 0; j < 32; j += 8)
        dst[(size_t)(d0 + ty + j) * HID + h0 + tx] = f2bf(tile[tx][ty + j]);
}

// ---------------------------------------------------------------------------
__global__ void route_kernel(const int* __restrict__ sel,
                             const float* __restrict__ wts,
                             int* __restrict__ meta,
                             int* __restrict__ stok,
                             int* __restrict__ sinv) {
    __shared__ int lc[256][NEXP];
    __shared__ int tot[NEXP];
    __shared__ int s_off[NEXP + 1];
    int t = threadIdx.x;
    int cnt[NEXP];
#pragma unroll
    for (int e = 0; e < NEXP; e++) cnt[e] = 0;
    int base = t * (NSLOT / 256);
    for (int i = 0; i < NSLOT / 256; i++) cnt[sel[base + i]]++;
#pragma unroll
    for (int e = 0; e < NEXP; e++) lc[t][e] = cnt[e];
    __syncthreads();
    if (t < NEXP) {
        int run = 0;
        for (int i = 0; i < 256; i++) { int v = lc[i][t]; lc[i][t] = run; run += v; }
        tot[t] = run;
    }
    __syncthreads();
    if (t == 0) {
        int o = 0;
        for (int e = 0; e < NEXP; e++) { s_off[e] = o; o += tot[e]; }
        s_off[NEXP] = o;
        for (int e = 0; e <= NEXP; e++) meta[e] = s_off[e];
        int nt = 0;
        for (int e = 0; e < NEXP; e++) {
            int c = s_off[e + 1] - s_off[e];
            int m = (c + BM - 1) / BM;
            for (int i = 0; i < m; i++) { meta[32 + 2 * nt] = e; meta[33 + 2 * nt] = i; nt++; }
        }
        meta[16] = nt;
    }
    __syncthreads();
    int cur[NEXP];
#pragma unroll
    for (int e = 0; e < NEXP; e++) cur[e] = s_off[e] + lc[t][e];
    for (int i = 0; i < NSLOT / 256; i++) {
        int slot = base + i;
        int e = sel[slot];
        int pos = cur[e]++;
        stok[pos] = slot >> 1;
        sinv[slot] = pos;
    }
}

// ---------------------------------------------------------------------------
// GEMM1 (8-phase): act = gelu(x@Wg^T) * (x@Wu^T).
// Tile: 256 slots x (128 U-cols + 128 G-cols), BK=64, 8 waves (2M x 4N).
// LDS: A 2x2x[128x64] (64KB) + U 2x[128x64] (32KB) + G 2x[128x64] (32KB).
// Per iteration: 2 K-tiles, 8 phases; one half-tile staged per phase;
// vmcnt(2) at phases 4/8 only. Stage targets always a region whose reads
// drained >=1 barrier earlier (read order per tile: {A-lo+U:12, G:4, A-hi:8, -:0}).
__global__ __launch_bounds__(512, 2) void gemm1_kernel(
    const ushort_t* __restrict__ X,
    const ushort_t* __restrict__ U,
    const ushort_t* __restrict__ G,
    const int* __restrict__ meta,
    const int* __restrict__ stok,
    ushort_t* __restrict__ act) {
    __shared__ __align__(16) ushort_t AT[2][2][128 * BK];   // 64 KB
    __shared__ __align__(16) ushort_t UT[2][128 * BK];      // 32 KB
    __shared__ __align__(16) ushort_t GT[2][128 * BK];      // 32 KB
    __shared__ int s_tok[BM1];

    // derive (expert, m-tile) for this 256-row tile from per-expert offsets
    int tile = blockIdx.x;
    int e = -1, mt = 0, accT = 0;
#pragma unroll
    for (int ee = 0; ee < NEXP; ee++) {
        int c = meta[ee + 1] - meta[ee];
        int m = (c + BM1 - 1) >> 8;
        if (tile >= accT && tile < accT + m) { e = ee; mt = tile - accT; }
        accT += m;
    }
    if (e < 0) return;
    int off = meta[e];
    int cnt = meta[e + 1] - off;
    int m0 = mt * BM1;
    int n0 = blockIdx.y * 128;

    int tid = threadIdx.x;
    if (tid < BM1) {
        int r = m0 + tid;
        if (r >= cnt) r = cnt - 1;
        s_tok[tid] = stok[off + r];
    }
    __syncthreads();   // s_tok visible; clean vmcnt baseline for the pipeline

    int lane = tid & 63;
    int w = tid >> 6;        // 0..7
    int wm = w >> 2;         // 0..1  (row half)
    int wn = w & 3;          // 0..3  (32-col group)
    int srow = lane >> 3;
    int schunk = lane & 7;
    int gchunk = schunk ^ srow;     // pre-swizzled source chunk (R2-verified)
    int r4 = lane & 15;
    int q = lane >> 4;
    int sw7 = r4 & 7;

    const ushort_t* Xp[2][2];
#pragma unroll
    for (int h = 0; h < 2; h++)
#pragma unroll
        for (int j = 0; j < 2; j++) {
            int r = h * 128 + w * 16 + j * 8 + srow;
            Xp[h][j] = X + (size_t)s_tok[r] * IN_DIM + gchunk * 8;
        }
    const ushort_t* Ue = U + ((size_t)e * HID + n0) * IN_DIM;
    const ushort_t* Ge = G + ((size_t)e * HID + n0) * IN_DIM;
    const ushort_t* Upt[2];
    const ushort_t* Gpt[2];
#pragma unroll
    for (int j = 0; j < 2; j++) {
        int r = w * 16 + j * 8 + srow;
        Upt[j] = Ue + (size_t)r * IN_DIM + gchunk * 8;
        Gpt[j] = Ge + (size_t)r * IN_DIM + gchunk * 8;
    }

    f32x4 accH[8][2], accG[8][2];
#pragma unroll
    for (int mi = 0; mi < 8; mi++)
#pragma unroll
        for (int ni = 0; ni < 2; ni++) {
            accH[mi][ni] = (f32x4){0.f, 0.f, 0.f, 0.f};
            accG[mi][ni] = (f32x4){0.f, 0.f, 0.f, 0.f};
        }

    bf16x8 a[4][2], bu[2][2], bg[2][2];

#define ST_A(b, h, kt) {                                                   \
        async16(Xp[h][0] + (kt), &AT[b][h][(w * 16) * BK]);                \
        async16(Xp[h][1] + (kt), &AT[b][h][(w * 16 + 8) * BK]); }
#define ST_U(b, kt) {                                                      \
        async16(Upt[0] + (kt), &UT[b][(w * 16) * BK]);                     \
        async16(Upt[1] + (kt), &UT[b][(w * 16 + 8) * BK]); }
#define ST_G(b, kt) {                                                      \
        async16(Gpt[0] + (kt), &GT[b][(w * 16) * BK]);                     \
        async16(Gpt[1] + (kt), &GT[b][(w * 16 + 8) * BK]); }

#define RD_A(b, mb) {                                                      \
        _Pragma("unroll") for (int mi = 0; mi < 4; mi++)                   \
        _Pragma("unroll") for (int kh = 0; kh < 2; kh++)                   \
            a[mi][kh] = *(const bf16x8*)&AT[b][wm][                        \
                ((mb) + mi * 16 + r4) * BK + (((kh * 4 + q) ^ sw7) << 3)]; }
#define RD_U(b) {                                                          \
        _Pragma("unroll") for (int ni = 0; ni < 2; ni++)                   \
        _Pragma("unroll") for (int kh = 0; kh < 2; kh++)                   \
            bu[ni][kh] = *(const bf16x8*)&UT[b][                           \
                (wn * 32 + ni * 16 + r4) * BK + (((kh * 4 + q) ^ sw7) << 3)]; }
#define RD_G(b) {                                                          \
        _Pragma("unroll") for (int ni = 0; ni < 2; ni++)                   \
        _Pragma("unroll") for (int kh = 0; kh < 2; kh++)                   \
            bg[ni][kh] = *(const bf16x8*)&GT[b][                           \
                (wn * 32 + ni * 16 + r4) * BK + (((kh * 4 + q) ^ sw7) << 3)]; }

#define MM(ACC, mb2, BB) {                                                 \
        _Pragma("unroll") for (int mi = 0; mi < 4; mi++)                   \
        _Pragma("unroll") for (int ni = 0; ni < 2; ni++)                   \
        _Pragma("unroll") for (int kh = 0; kh < 2; kh++)                   \
            ACC[(mb2) + mi][ni] = __builtin_amdgcn_mfma_f32_16x16x32_bf16( \
                a[mi][kh], BB[ni][kh], ACC[(mb2) + mi][ni], 0, 0, 0); }

#define BARRIER __builtin_amdgcn_s_barrier()
#define LGKM0 asm volatile("s_waitcnt lgkmcnt(0)" ::: "memory")
#define VMW2 asm volatile("s_waitcnt vmcnt(2)" ::: "memory")
#define PRIO1 __builtin_amdgcn_s_setprio(1)
#define PRIO0 __builtin_amdgcn_s_setprio(0)

    // prologue: tile0 fully (A0,A1,U,G) + tile1 A-h0 -> 10 loads/thread
    ST_A(0, 0, 0); ST_A(0, 1, 0); ST_U(0, 0); ST_G(0, 0);
    ST_A(1, 0, BK);
    VMW2; BARRIER;           // tile0 landed; tile1:A0 (2 loads) in flight

    for (int it = 0; it < 8; it++) {
        int t = 2 * it;
        int k1 = (t + 1) * BK;
        int k2 = (t + 2 < 16 ? t + 2 : 15) * BK;   // clamp keeps vmcnt uniform
        int k3 = (t + 3 < 16 ? t + 3 : 15) * BK;
        // ph1: Q(m-lo x U) of tile t
        RD_A(0, 0); RD_U(0);
        ST_A(1, 1, k1);
        BARRIER; LGKM0;
        PRIO1; MM(accH, 0, bu); PRIO0; BARRIER;
        // ph2: Q(m-lo x G)
        RD_G(0);
        ST_U(1, k1);
        BARRIER; LGKM0;
        PRIO1; MM(accG, 0, bg); PRIO0; BARRIER;
        // ph3: Q(m-hi x G)
        RD_A(0, 64);
        ST_G(1, k1);
        BARRIER; LGKM0;
        PRIO1; MM(accG, 4, bg); PRIO0; BARRIER;
        // ph4: Q(m-hi x U); buf0 A-h0 free after ph3 -> stage t+2
        ST_A(0, 0, k2);
        VMW2; BARRIER;       // tile t+1 fully landed; t+2:A0 in flight
        PRIO1; MM(accH, 4, bu); PRIO0; BARRIER;
        // ph5: Q(m-lo x U) of tile t+1
        RD_A(1, 0); RD_U(1);
        ST_A(0, 1, k2);
        BARRIER; LGKM0;
        PRIO1; MM(accH, 0, bu); PRIO0; BARRIER;
        // ph6: Q(m-lo x G)
        RD_G(1);
        ST_U(0, k2);
        BARRIER; LGKM0;
        PRIO1; MM(accG, 0, bg); PRIO0; BARRIER;
        // ph7: Q(m-hi x G)
        RD_A(1, 64);
        ST_G(0, k2);
        BARRIER; LGKM0;
        PRIO1; MM(accG, 4, bg); PRIO0; BARRIER;
        // ph8: Q(m-hi x U); buf1 A-h0 free after ph7 -> stage t+3
        ST_A(1, 0, k3);
        VMW2; BARRIER;       // tile t+2 fully landed; t+3:A0 in flight
        PRIO1; MM(accH, 4, bu); PRIO0; BARRIER;
    }

#pragma unroll
    for (int mf = 0; mf < 8; mf++) {
#pragma unroll
        for (int r = 0; r < 4; r++) {
            int row_local = wm * 128 + mf * 16 + q * 4 + r;
            int grow = m0 + row_local;
            if (grow >= cnt) continue;
            size_t orow = (size_t)(off + grow) * HID + n0 + wn * 32;
#pragma unroll
            for (int ni = 0; ni < 2; ni++) {
                float h = accH[mf][ni][r];
                float g = accG[mf][ni][r];
                act[orow + ni * 16 + r4] = f2bf(gelu_tanh(g) * h);
            }
        }
    }
#undef ST_A
#undef ST_U
#undef ST_G
#undef RD_A
#undef RD_U
#undef RD_G
#undef MM
}

// ---------------------------------------------------------------------------
// GEMM2: y[pos] = act[pos] @ Wd (per-slot raw output, no weights, no atomics)
// Tile 128x128, BK=64, dbuf. grid.x = tile, grid.y = n-block (8). (unchanged)
__global__ __launch_bounds__(256) void gemm2_kernel(
    const ushort_t* __restrict__ act,
    const ushort_t* __restrict__ DT,
    const int* __restrict__ meta,
    float* __restrict__ y) {            // [NSLOT][IN_DIM] fp32
    __shared__ __align__(16) ushort_t AT[2][BM * BK];   // 32 KB
    __shared__ __align__(16) ushort_t BT[2][BM * BK];   // 32 KB

    int tile = blockIdx.x;
    if (tile >= meta[16]) return;
    int e = meta[32 + 2 * tile];
    int mt = meta[33 + 2 * tile];
    int off = meta[e];
    int cnt = meta[e + 1] - off;
    int m0 = mt * BM;
    int n0 = blockIdx.y * 128;

    int tid = threadIdx.x;
    int lane = tid & 63;
    int w = tid >> 6;
    int wr = w >> 1, wc = w & 1;
    int srow = lane >> 3;
    int schunk = lane & 7;
    int gchunk = schunk ^ srow;

    const ushort_t* Ae = act + (size_t)off * HID;
    const ushort_t* Be = DT + ((size_t)e * IN_DIM + n0) * HID;

    const ushort_t* ap[4];
    const ushort_t* bp[4];
#pragma unroll
    for (int i = 0; i < 4; i++) {
        int r = w * 32 + i * 8 + srow;
        int ar = m0 + r; if (ar >= cnt) ar = cnt - 1;
        ap[i] = Ae + (size_t)ar * HID + gchunk * 8;
        bp[i] = Be + (size_t)r * HID + gchunk * 8;
    }

    f32x4 acc[4][4];
#pragma unroll
    for (int mi = 0; mi < 4; mi++)
#pragma unroll
        for (int ni = 0; ni < 4; ni++) acc[mi][ni] = (f32x4){0.f, 0.f, 0.f, 0.f};

    int r4 = lane & 15;
    int q = lane >> 4;
    int sw7 = r4 & 7;

#define G2_ISSUE(s)                                                        \
    {                                                                      \
        int _b = (s) & 1;                                                  \
        int _k0 = (s) * BK;                                                \
        _Pragma("unroll")                                                  \
        for (int i = 0; i < 4; i++) {                                      \
            async16(ap[i] + _k0, &AT[_b][(w * 32 + i * 8) * BK]);          \
            async16(bp[i] + _k0, &BT[_b][(w * 32 + i * 8) * BK]);          \
        }                                                                  \
    }

#define G2_COMPUTE(s)                                                      \
    {                                                                      \
        int _b = (s) & 1;                                                  \
        _Pragma("unroll")                                                  \
        for (int kk = 0; kk < BK; kk += 32) {                              \
            int c = (kk >> 3) + q;                                         \
            int cs = ((c ^ sw7) << 3);                                     \
            bf16x8 a[4], b[4];                                             \
            _Pragma("unroll")                                              \
            for (int i = 0; i < 4; i++) {                                  \
                a[i] = *(const bf16x8*)&AT[_b][(wr * 64 + i * 16 + r4) * BK + cs]; \
                b[i] = *(const bf16x8*)&BT[_b][(wc * 64 + i * 16 + r4) * BK + cs]; \
            }                                                              \
            _Pragma("unroll")                                              \
            for (int mi = 0; mi < 4; mi++)                                 \
                _Pragma("unroll")                                          \
                for (int ni = 0; ni < 4; ni++)                             \
                    acc[mi][ni] = __builtin_amdgcn_mfma_f32_16x16x32_bf16( \
                        a[mi], b[ni], acc[mi][ni], 0, 0, 0);               \
        }                                                                  \
    }

    const int NK = HID / BK;   // 32
    G2_ISSUE(0);
    for (int s = 0; s < NK - 1; s++) {
        G2_ISSUE(s + 1);
        wait8_barrier();
        G2_COMPUTE(s);
        lds_barrier();
    }
    wait0_barrier();
    G2_COMPUTE(NK - 1);

#pragma unroll
    for (int mi = 0; mi < 4; mi++) {
#pragma unroll
        for (int r = 0; r < 4; r++) {
            int row_local = wr * 64 + mi * 16 + q * 4 + r;
            int grow = m0 + row_local;
            if (grow >= cnt) continue;
            float* orow = y + (size_t)(off + grow) * IN_DIM + n0 + wc * 64;
#pragma unroll
            for (int ni = 0; ni < 4; ni++)
                orow[ni * 16 + r4] = acc[mi][ni][r];
        }
    }
}

// ---------------------------------------------------------------------------
// combine: out[tok] = w0*y[sinv[2tok]] + w1*y[sinv[2tok+1]]. One block/token.
__global__ __launch_bounds__(256) void combine_kernel(
    const float* __restrict__ y,
    const float* __restrict__ wts,
    const int* __restrict__ sinv,
    float* __restrict__ out) {
    int tok = blockIdx.x;
    int c = threadIdx.x;              // 256 threads x float4 = 1024 floats
    int p0 = sinv[tok * 2], p1 = sinv[tok * 2 + 1];
    float w0 = wts[tok * 2], w1 = wts[tok * 2 + 1];
    float4 a = *(const float4*)(y + (size_t)p0 * IN_DIM + c * 4);
    float4 b = *(const float4*)(y + (size_t)p1 * IN_DIM + c * 4);
    float4 o;
    o.x = w0 * a.x + w1 * b.x;
    o.y = w0 * a.y + w1 * b.y;
    o.z = w0 * a.z + w1 * b.z;
    o.w = w0 * a.w + w1 * b.w;
    *(float4*)(out + (size_t)tok * IN_DIM + c * 4) = o;
}

// ---------------------------------------------------------------------------
extern "C" void kernel_launch(void* const* d_in, const int* in_sizes, int n_in,
                              void* d_out, int out_size, void* d_ws, size_t ws_size,
                              hipStream_t stream) {
    const float* inp  = (const float*)d_in[0];
    const float* wts  = (const float*)d_in[1];
    const float* up   = (const float*)d_in[2];
    const float* gate = (const float*)d_in[3];
    const float* down = (const float*)d_in[4];
    const int*   sel  = (const int*)d_in[5];
    float* out = (float*)d_out;

    // workspace layout: y (fp32, 64 MB) ALIASES inp_bf/up_bf/part of gate_bf —
    // safe because gemm2 (writes y) is stream-ordered after gemm1 (last reader
    // of inp/up/gate_bf), and casts rewrite them every call.
    char* ws = (char*)d_ws;
    ushort_t* inp_bf  = (ushort_t*)(ws);
    ushort_t* up_bf   = (ushort_t*)(ws + 16777216);
    ushort_t* gate_bf = (ushort_t*)(ws + 50331648);
    ushort_t* down_bf = (ushort_t*)(ws + 83886080);
    ushort_t* act     = (ushort_t*)(ws + 117440512);
    int*      stok    = (int*)(ws + 184549376);
    int*      sinv    = (int*)(ws + 184614912);
    int*      meta    = (int*)(ws + 184680448);
    float*    y       = (float*)(ws);            // 64 MB, aliases bf16 inputs

    cast_bf16_kernel<<<(SEQ * IN_DIM) / 1024, 256, 0, stream>>>(inp, inp_bf, SEQ * IN_DIM);
    cast_bf16_kernel<<<(NEXP * HID * IN_DIM) / 1024, 256, 0, stream>>>(up, up_bf, NEXP * HID * IN_DIM);
    cast_bf16_kernel<<<(NEXP * HID * IN_DIM) / 1024, 256, 0, stream>>>(gate, gate_bf, NEXP * HID * IN_DIM);
    transpose_cast_kernel<<<dim3(IN_DIM / 32, HID / 32, NEXP), 256, 0, stream>>>(down, down_bf);
    route_kernel<<<1, 256, 0, stream>>>(sel, wts, meta, stok, sinv);
    gemm1_kernel<<<dim3(MAX_T1, HID / 128), 512, 0, stream>>>(inp_bf, up_bf, gate_bf, meta, stok, act);
    gemm2_kernel<<<dim3(MAX_TILES, IN_DIM / 128), 256, 0, stream>>>(act, down_bf, meta, y);
    combine_kernel<<<SEQ, 256, 0, stream>>>(y, wts, sinv, out);
}

// Round 2
// 567.135 us; speedup vs baseline: 1.0765x; 1.0108x over previous
//
#include <hip/hip_runtime.h>

// ---------------------------------------------------------------------------
// MoE FFN: SEQ=8192, IN_DIM=1024, HID=2048, 8 experts, topk=2, gelu(tanh) gate
// R5: both GEMMs on the 256-row 8-phase skeleton (T3+T4 counted vmcnt, T5
// setprio, T2 swizzle). K-loop rebuilt as fixed 2-K-tile body with
// compile-time buffer indices / stage offsets + pointer advance, peeled tail
// (correct vmcnt(0) instead of clamped re-stage) -> kills the VALU address
// recomputation R4's counters showed (VALUBusy 25%). Bijective XCD-chunked
// grid swizzle on both GEMMs.
// ---------------------------------------------------------------------------

#define SEQ 8192
#define IN_DIM 1024
#define HID 2048
#define NEXP 8
#define TOPK 2
#define NSLOT (SEQ * TOPK)

#define BM 128            // legacy (route_kernel tile table, unused by gemms)
#define BK 64
#define BM1 256
#define MAX_T1 72

typedef unsigned short ushort_t;
typedef __bf16 bf16x8 __attribute__((ext_vector_type(8)));
typedef float f32x4 __attribute__((ext_vector_type(4)));

__device__ __forceinline__ ushort_t f2bf(float f) {
    union { float f; unsigned u; } v;
    v.f = f;
    unsigned r = v.u + 0x7FFFu + ((v.u >> 16) & 1u);
    return (ushort_t)(r >> 16);
}

__device__ __forceinline__ float gelu_tanh(float x) {
    float u = 0.7978845608028654f * x * (1.0f + 0.044715f * x * x);
    return x / (1.0f + __expf(-2.0f * u));
}

__device__ __forceinline__ void async16(const void* g, void* l) {
    __builtin_amdgcn_global_load_lds(
        (const __attribute__((address_space(1))) unsigned int*)g,
        (__attribute__((address_space(3))) unsigned int*)l, 16, 0, 0);
}

// ---------------------------------------------------------------------------
__global__ void cast_bf16_kernel(const float* __restrict__ in,
                                 ushort_t* __restrict__ out, int n) {
    int i = (blockIdx.x * blockDim.x + threadIdx.x) * 4;
    if (i >= n) return;
    float4 v = *(const float4*)(in + i);
    union { ushort_t u[4]; uint2 v; } o;
    o.u[0] = f2bf(v.x); o.u[1] = f2bf(v.y);
    o.u[2] = f2bf(v.z); o.u[3] = f2bf(v.w);
    *(uint2*)(out + i) = o.v;
}

// down_proj [8][2048][1024] fp32 -> [8][1024][2048] bf16
__global__ void transpose_cast_kernel(const float* __restrict__ in,
                                      ushort_t* __restrict__ out) {
    __shared__ float tile[32][33];
    int e = blockIdx.z;
    int d0 = blockIdx.x * 32, h0 = blockIdx.y * 32;
    int tx = threadIdx.x & 31, ty = threadIdx.x >> 5;
    const float* src = in + (size_t)e * HID * IN_DIM;
    for (int j = 0; j < 32; j += 8)
        tile[ty + j][tx] = src[(size_t)(h0 + ty + j) * IN_DIM + d0 + tx];
    __syncthreads();
    ushort_t* dst = out + (size_t)e * IN_DIM * HID;
    for (int j = 0; j < 32; j += 8)
        dst[(size_t)(d0 + ty + j) * HID + h0 + tx] = f2bf(tile[tx][ty + j]);
}

// ---------------------------------------------------------------------------
__global__ void route_kernel(const int* __restrict__ sel,
                             const float* __restrict__ wts,
                             int* __restrict__ meta,
                             int* __restrict__ stok,
                             int* __restrict__ sinv) {
    __shared__ int lc[256][NEXP];
    __shared__ int tot[NEXP];
    __shared__ int s_off[NEXP + 1];
    int t = threadIdx.x;
    int cnt[NEXP];
#pragma unroll
    for (int e = 0; e < NEXP; e++) cnt[e] = 0;
    int base = t * (NSLOT / 256);
    for (int i = 0; i < NSLOT / 256; i++) cnt[sel[base + i]]++;
#pragma unroll
    for (int e = 0; e < NEXP; e++) lc[t][e] = cnt[e];
    __syncthreads();
    if (t < NEXP) {
        int run = 0;
        for (int i = 0; i < 256; i++) { int v = lc[i][t]; lc[i][t] = run; run += v; }
        tot[t] = run;
    }
    __syncthreads();
    if (t == 0) {
        int o = 0;
        for (int e = 0; e < NEXP; e++) { s_off[e] = o; o += tot[e]; }
        s_off[NEXP] = o;
        for (int e = 0; e <= NEXP; e++) meta[e] = s_off[e];
        int nt = 0;
        for (int e = 0; e < NEXP; e++) {
            int c = s_off[e + 1] - s_off[e];
            int m = (c + BM - 1) / BM;
            for (int i = 0; i < m; i++) { meta[32 + 2 * nt] = e; meta[33 + 2 * nt] = i; nt++; }
        }
        meta[16] = nt;
    }
    __syncthreads();
    int cur[NEXP];
#pragma unroll
    for (int e = 0; e < NEXP; e++) cur[e] = s_off[e] + lc[t][e];
    for (int i = 0; i < NSLOT / 256; i++) {
        int slot = base + i;
        int e = sel[slot];
        int pos = cur[e]++;
        stok[pos] = slot >> 1;
        sinv[slot] = pos;
    }
}

// ---------------------------------------------------------------------------
// Shared 8-phase K-loop skeleton (both gemms). Locals required at expansion
// site: AT[2][2][128*BK], UT[2][128*BK], GT[2][128*BK], pA[2][2], pU[2],
// pG[2], a[4][2], bu[2][2], bg[2][2], accH[8][2], accG[8][2],
// w, wm, wn, r4, q, sw7.
// Body covers 2 K-tiles (t in buf0, t+1 in buf1); pointers sit at tile t;
// stage offsets are compile-time (+64/+128/+192 elements). vmcnt(2) only at
// phases 4/8; one half-tile (2 loads) stays in flight across each wait.
// ---------------------------------------------------------------------------
#define ST_A(b, h, koff) {                                                 \
        async16(pA[h][0] + (koff), &AT[b][h][(w * 16) * BK]);              \
        async16(pA[h][1] + (koff), &AT[b][h][(w * 16 + 8) * BK]); }
#define ST_U(b, koff) {                                                    \
        async16(pU[0] + (koff), &UT[b][(w * 16) * BK]);                    \
        async16(pU[1] + (koff), &UT[b][(w * 16 + 8) * BK]); }
#define ST_G(b, koff) {                                                    \
        async16(pG[0] + (koff), &GT[b][(w * 16) * BK]);                    \
        async16(pG[1] + (koff), &GT[b][(w * 16 + 8) * BK]); }

#define RD_A(b, mb) {                                                      \
        _Pragma("unroll") for (int mi = 0; mi < 4; mi++)                   \
        _Pragma("unroll") for (int kh = 0; kh < 2; kh++)                   \
            a[mi][kh] = *(const bf16x8*)&AT[b][wm][                        \
                ((mb) + mi * 16 + r4) * BK + (((kh * 4 + q) ^ sw7) << 3)]; }
#define RD_U(b) {                                                          \
        _Pragma("unroll") for (int ni = 0; ni < 2; ni++)                   \
        _Pragma("unroll") for (int kh = 0; kh < 2; kh++)                   \
            bu[ni][kh] = *(const bf16x8*)&UT[b][                           \
                (wn * 32 + ni * 16 + r4) * BK + (((kh * 4 + q) ^ sw7) << 3)]; }
#define RD_G(b) {                                                          \
        _Pragma("unroll") for (int ni = 0; ni < 2; ni++)                   \
        _Pragma("unroll") for (int kh = 0; kh < 2; kh++)                   \
            bg[ni][kh] = *(const bf16x8*)&GT[b][                           \
                (wn * 32 + ni * 16 + r4) * BK + (((kh * 4 + q) ^ sw7) << 3)]; }

#define MM(ACC, mb2, BB) {                                                 \
        _Pragma("unroll") for (int mi = 0; mi < 4; mi++)                   \
        _Pragma("unroll") for (int ni = 0; ni < 2; ni++)                   \
        _Pragma("unroll") for (int kh = 0; kh < 2; kh++)                   \
            ACC[(mb2) + mi][ni] = __builtin_amdgcn_mfma_f32_16x16x32_bf16( \
                a[mi][kh], BB[ni][kh], ACC[(mb2) + mi][ni], 0, 0, 0); }

#define BARRIER __builtin_amdgcn_s_barrier()
#define LGKM0 asm volatile("s_waitcnt lgkmcnt(0)" ::: "memory")
#define VMW2 asm volatile("s_waitcnt vmcnt(2)" ::: "memory")
#define VMW0 asm volatile("s_waitcnt vmcnt(0)" ::: "memory")
#define PRIO1 __builtin_amdgcn_s_setprio(1)
#define PRIO0 __builtin_amdgcn_s_setprio(0)

// prologue: tile0 fully (A-lo,A-hi,U,G -> buf0) + tile1 A-lo -> 10 loads
#define KPRO                                                               \
    ST_A(0, 0, 0); ST_A(0, 1, 0); ST_U(0, 0); ST_G(0, 0);                  \
    ST_A(1, 0, 64);                                                        \
    VMW2; BARRIER;

#define KBODY_FULL                                                         \
    RD_A(0, 0); RD_U(0); ST_A(1, 1, 64); BARRIER; LGKM0;                   \
    PRIO1; MM(accH, 0, bu); PRIO0; BARRIER;                                \
    RD_G(0); ST_U(1, 64); BARRIER; LGKM0;                                  \
    PRIO1; MM(accG, 0, bg); PRIO0; BARRIER;                                \
    RD_A(0, 64); ST_G(1, 64); BARRIER; LGKM0;                              \
    PRIO1; MM(accG, 4, bg); PRIO0; BARRIER;                                \
    ST_A(0, 0, 128); VMW2; BARRIER;                                        \
    PRIO1; MM(accH, 4, bu); PRIO0; BARRIER;                                \
    RD_A(1, 0); RD_U(1); ST_A(0, 1, 128); BARRIER; LGKM0;                  \
    PRIO1; MM(accH, 0, bu); PRIO0; BARRIER;                                \
    RD_G(1); ST_U(0, 128); BARRIER; LGKM0;                                 \
    PRIO1; MM(accG, 0, bg); PRIO0; BARRIER;                                \
    RD_A(1, 64); ST_G(0, 128); BARRIER; LGKM0;                             \
    PRIO1; MM(accG, 4, bg); PRIO0; BARRIER;                                \
    ST_A(1, 0, 192); VMW2; BARRIER;                                        \
    PRIO1; MM(accH, 4, bu); PRIO0; BARRIER;

#define KBODY_ADV {                                                        \
    pA[0][0] += 128; pA[0][1] += 128; pA[1][0] += 128; pA[1][1] += 128;    \
    pU[0] += 128; pU[1] += 128; pG[0] += 128; pG[1] += 128; }

// tail: tiles N-2 (buf0), N-1 (buf1); stage only tile N-1 A-hi/U/G;
// vmcnt(0) at phase 4 (everything outstanding is tile N-1 and all needed).
#define KBODY_TAIL                                                         \
    RD_A(0, 0); RD_U(0); ST_A(1, 1, 64); BARRIER; LGKM0;                   \
    PRIO1; MM(accH, 0, bu); PRIO0; BARRIER;                                \
    RD_G(0); ST_U(1, 64); BARRIER; LGKM0;                                  \
    PRIO1; MM(accG, 0, bg); PRIO0; BARRIER;                                \
    RD_A(0, 64); ST_G(1, 64); BARRIER; LGKM0;                              \
    PRIO1; MM(accG, 4, bg); PRIO0; BARRIER;                                \
    VMW0; BARRIER;                                                         \
    PRIO1; MM(accH, 4, bu); PRIO0; BARRIER;                                \
    RD_A(1, 0); RD_U(1); BARRIER; LGKM0;                                   \
    PRIO1; MM(accH, 0, bu); PRIO0; BARRIER;                                \
    RD_G(1); BARRIER; LGKM0;                                               \
    PRIO1; MM(accG, 0, bg); PRIO0; BARRIER;                                \
    RD_A(1, 64); BARRIER; LGKM0;                                           \
    PRIO1; MM(accG, 4, bg); PRIO0; BARRIER;                                \
    PRIO1; MM(accH, 4, bu); PRIO0;

// derive (expert, m-tile) for a 256-row tile index from per-expert offsets
#define TILE_DERIVE(tile)                                                  \
    int e = -1, mt = 0, accT = 0;                                          \
    _Pragma("unroll")                                                      \
    for (int ee = 0; ee < NEXP; ee++) {                                    \
        int c = meta[ee + 1] - meta[ee];                                   \
        int m = (c + BM1 - 1) >> 8;                                        \
        if ((tile) >= accT && (tile) < accT + m) { e = ee; mt = (tile) - accT; } \
        accT += m;                                                         \
    }                                                                      \
    if (e < 0) return;                                                     \
    int off = meta[e];                                                     \
    int cnt = meta[e + 1] - off;                                           \
    int m0 = mt * BM1;

// ---------------------------------------------------------------------------
// GEMM1: act = gelu(x@Wg^T) * (x@Wu^T). Tile 256 x (128 U-cols + 128 G-cols).
__global__ __launch_bounds__(512, 2) void gemm1_kernel(
    const ushort_t* __restrict__ X,
    const ushort_t* __restrict__ U,
    const ushort_t* __restrict__ G,
    const int* __restrict__ meta,
    const int* __restrict__ stok,
    ushort_t* __restrict__ act) {
    __shared__ __align__(16) ushort_t AT[2][2][128 * BK];   // 64 KB
    __shared__ __align__(16) ushort_t UT[2][128 * BK];      // 32 KB
    __shared__ __align__(16) ushort_t GT[2][128 * BK];      // 32 KB
    __shared__ int s_tok[BM1];

    // XCD-chunked bijective swizzle: 72*16 = 1152 = 8*144
    int id = blockIdx.x + MAX_T1 * blockIdx.y;
    int wi = (id & 7) * 144 + (id >> 3);
    int tile = wi % MAX_T1;
    int n0 = (wi / MAX_T1) * 128;

    TILE_DERIVE(tile);

    int tid = threadIdx.x;
    if (tid < BM1) {
        int r = m0 + tid;
        if (r >= cnt) r = cnt - 1;
        s_tok[tid] = stok[off + r];
    }
    __syncthreads();

    int lane = tid & 63;
    int w = tid >> 6;        // 0..7
    int wm = w >> 2;         // 0..1  (row half)
    int wn = w & 3;          // 0..3  (32-col group)
    int srow = lane >> 3;
    int schunk = lane & 7;
    int gchunk = schunk ^ srow;     // pre-swizzled source chunk
    int r4 = lane & 15;
    int q = lane >> 4;
    int sw7 = r4 & 7;

    const ushort_t* pA[2][2];
#pragma unroll
    for (int h = 0; h < 2; h++)
#pragma unroll
        for (int j = 0; j < 2; j++) {
            int r = h * 128 + w * 16 + j * 8 + srow;
            pA[h][j] = X + (size_t)s_tok[r] * IN_DIM + gchunk * 8;
        }
    const ushort_t* Ue = U + ((size_t)e * HID + n0) * IN_DIM;
    const ushort_t* Ge = G + ((size_t)e * HID + n0) * IN_DIM;
    const ushort_t* pU[2];
    const ushort_t* pG[2];
#pragma unroll
    for (int j = 0; j < 2; j++) {
        int r = w * 16 + j * 8 + srow;
        pU[j] = Ue + (size_t)r * IN_DIM + gchunk * 8;
        pG[j] = Ge + (size_t)r * IN_DIM + gchunk * 8;
    }

    f32x4 accH[8][2], accG[8][2];
#pragma unroll
    for (int mi = 0; mi < 8; mi++)
#pragma unroll
        for (int ni = 0; ni < 2; ni++) {
            accH[mi][ni] = (f32x4){0.f, 0.f, 0.f, 0.f};
            accG[mi][ni] = (f32x4){0.f, 0.f, 0.f, 0.f};
        }

    bf16x8 a[4][2], bu[2][2], bg[2][2];

    KPRO;
#pragma unroll 1
    for (int i = 0; i < (IN_DIM / BK) / 2 - 1; ++i) {   // 7 bodies
        KBODY_FULL;
        KBODY_ADV;
    }
    KBODY_TAIL;

#pragma unroll
    for (int mf = 0; mf < 8; mf++) {
#pragma unroll
        for (int r = 0; r < 4; r++) {
            int row_local = wm * 128 + mf * 16 + q * 4 + r;
            int grow = m0 + row_local;
            if (grow >= cnt) continue;
            size_t orow = (size_t)(off + grow) * HID + n0 + wn * 32;
#pragma unroll
            for (int ni = 0; ni < 2; ni++) {
                float h = accH[mf][ni][r];
                float g = accG[mf][ni][r];
                act[orow + ni * 16 + r4] = f2bf(gelu_tanh(g) * h);
            }
        }
    }
}

// ---------------------------------------------------------------------------
// GEMM2: y[pos] = act[pos] @ Wd. Same skeleton: tile 256 x 256 (B-lo/B-hi),
// K = HID = 2048 (16 bodies). U-stream = DT cols n0..n0+127, G-stream = +128.
__global__ __launch_bounds__(512, 2) void gemm2_kernel(
    const ushort_t* __restrict__ act,
    const ushort_t* __restrict__ DT,
    const int* __restrict__ meta,
    float* __restrict__ y) {            // [NSLOT][IN_DIM] fp32
    __shared__ __align__(16) ushort_t AT[2][2][128 * BK];   // 64 KB
    __shared__ __align__(16) ushort_t UT[2][128 * BK];      // 32 KB
    __shared__ __align__(16) ushort_t GT[2][128 * BK];      // 32 KB

    // XCD-chunked bijective swizzle: 72*4 = 288 = 8*36
    int id = blockIdx.x + MAX_T1 * blockIdx.y;
    int wi = (id & 7) * 36 + (id >> 3);
    int tile = wi % MAX_T1;
    int n0 = (wi / MAX_T1) * 256;

    TILE_DERIVE(tile);

    int tid = threadIdx.x;
    int lane = tid & 63;
    int w = tid >> 6;
    int wm = w >> 2;
    int wn = w & 3;
    int srow = lane >> 3;
    int schunk = lane & 7;
    int gchunk = schunk ^ srow;
    int r4 = lane & 15;
    int q = lane >> 4;
    int sw7 = r4 & 7;

    const ushort_t* Ae = act + (size_t)off * HID;
    const ushort_t* pA[2][2];
#pragma unroll
    for (int h = 0; h < 2; h++)
#pragma unroll
        for (int j = 0; j < 2; j++) {
            int ar = m0 + h * 128 + w * 16 + j * 8 + srow;
            if (ar >= cnt) ar = cnt - 1;
            pA[h][j] = Ae + (size_t)ar * HID + gchunk * 8;
        }
    const ushort_t* Be = DT + ((size_t)e * IN_DIM + n0) * HID;
    const ushort_t* pU[2];
    const ushort_t* pG[2];
#pragma unroll
    for (int j = 0; j < 2; j++) {
        int r = w * 16 + j * 8 + srow;
        pU[j] = Be + (size_t)r * HID + gchunk * 8;
        pG[j] = Be + (size_t)(128 + r) * HID + gchunk * 8;
    }

    f32x4 accH[8][2], accG[8][2];    // accH = B-lo cols, accG = B-hi cols
#pragma unroll
    for (int mi = 0; mi < 8; mi++)
#pragma unroll
        for (int ni = 0; ni < 2; ni++) {
            accH[mi][ni] = (f32x4){0.f, 0.f, 0.f, 0.f};
            accG[mi][ni] = (f32x4){0.f, 0.f, 0.f, 0.f};
        }

    bf16x8 a[4][2], bu[2][2], bg[2][2];

    KPRO;
#pragma unroll 1
    for (int i = 0; i < (HID / BK) / 2 - 1; ++i) {   // 15 bodies
        KBODY_FULL;
        KBODY_ADV;
    }
    KBODY_TAIL;

#pragma unroll
    for (int mf = 0; mf < 8; mf++) {
#pragma unroll
        for (int r = 0; r < 4; r++) {
            int row_local = wm * 128 + mf * 16 + q * 4 + r;
            int grow = m0 + row_local;
            if (grow >= cnt) continue;
            float* orow = y + (size_t)(off + grow) * IN_DIM + n0 + wn * 32;
#pragma unroll
            for (int ni = 0; ni < 2; ni++) {
                orow[ni * 16 + r4] = accH[mf][ni][r];
                orow[128 + ni * 16 + r4] = accG[mf][ni][r];
            }
        }
    }
}

// ---------------------------------------------------------------------------
// combine: out[tok] = w0*y[sinv[2tok]] + w1*y[sinv[2tok+1]]. One block/token.
__global__ __launch_bounds__(256) void combine_kernel(
    const float* __restrict__ y,
    const float* __restrict__ wts,
    const int* __restrict__ sinv,
    float* __restrict__ out) {
    int tok = blockIdx.x;
    int c = threadIdx.x;              // 256 threads x float4 = 1024 floats
    int p0 = sinv[tok * 2], p1 = sinv[tok * 2 + 1];
    float w0 = wts[tok * 2], w1 = wts[tok * 2 + 1];
    float4 a = *(const float4*)(y + (size_t)p0 * IN_DIM + c * 4);
    float4 b = *(const float4*)(y + (size_t)p1 * IN_DIM + c * 4);
    float4 o;
    o.x = w0 * a.x + w1 * b.x;
    o.y = w0 * a.y + w1 * b.y;
    o.z = w0 * a.z + w1 * b.z;
    o.w = w0 * a.w + w1 * b.w;
    *(float4*)(out + (size_t)tok * IN_DIM + c * 4) = o;
}

// ---------------------------------------------------------------------------
extern "C" void kernel_launch(void* const* d_in, const int* in_sizes, int n_in,
                              void* d_out, int out_size, void* d_ws, size_t ws_size,
                              hipStream_t stream) {
    const float* inp  = (const float*)d_in[0];
    const float* wts  = (const float*)d_in[1];
    const float* up   = (const float*)d_in[2];
    const float* gate = (const float*)d_in[3];
    const float* down = (const float*)d_in[4];
    const int*   sel  = (const int*)d_in[5];
    float* out = (float*)d_out;

    // workspace layout: y (fp32, 64 MB) ALIASES inp_bf/up_bf/part of gate_bf —
    // safe because gemm2 (writes y) is stream-ordered after gemm1 (last reader
    // of inp/up/gate_bf), and casts rewrite them every call.
    char* ws = (char*)d_ws;
    ushort_t* inp_bf  = (ushort_t*)(ws);
    ushort_t* up_bf   = (ushort_t*)(ws + 16777216);
    ushort_t* gate_bf = (ushort_t*)(ws + 50331648);
    ushort_t* down_bf = (ushort_t*)(ws + 83886080);
    ushort_t* act     = (ushort_t*)(ws + 117440512);
    int*      stok    = (int*)(ws + 184549376);
    int*      sinv    = (int*)(ws + 184614912);
    int*      meta    = (int*)(ws + 184680448);
    float*    y       = (float*)(ws);            // 64 MB, aliases bf16 inputs

    cast_bf16_kernel<<<(SEQ * IN_DIM) / 1024, 256, 0, stream>>>(inp, inp_bf, SEQ * IN_DIM);
    cast_bf16_kernel<<<(NEXP * HID * IN_DIM) / 1024, 256, 0, stream>>>(up, up_bf, NEXP * HID * IN_DIM);
    cast_bf16_kernel<<<(NEXP * HID * IN_DIM) / 1024, 256, 0, stream>>>(gate, gate_bf, NEXP * HID * IN_DIM);
    transpose_cast_kernel<<<dim3(IN_DIM / 32, HID / 32, NEXP), 256, 0, stream>>>(down, down_bf);
    route_kernel<<<1, 256, 0, stream>>>(sel, wts, meta, stok, sinv);
    gemm1_kernel<<<dim3(MAX_T1, HID / 128), 512, 0, stream>>>(inp_bf, up_bf, gate_bf, meta, stok, act);
    gemm2_kernel<<<dim3(MAX_T1, IN_DIM / 256), 512, 0, stream>>>(act, down_bf, meta, y);
    combine_kernel<<<SEQ, 256, 0, stream>>>(y, wts, sinv, out);
}